// Round 25
// baseline (510.405 us; speedup 1.0000x reference)
//
#include <hip/hip_runtime.h>

#define HDIM 256
#define LNEPS 1e-5f

typedef float f32x4 __attribute__((ext_vector_type(4)));
typedef short bf16x8 __attribute__((ext_vector_type(8)));

static __device__ __forceinline__ unsigned short f2b(float f) {
  union { float f; unsigned u; } v; v.f = f;
  return (unsigned short)((v.u + 0x7fffu + ((v.u >> 16) & 1u)) >> 16);
}
static __device__ __forceinline__ unsigned pk2(float lo, float hi) {
  return (unsigned)f2b(lo) | ((unsigned)f2b(hi) << 16);
}

// ---------------- weight repack (all 4 matrices, one launch) ----------------
// WAVE-PRIVATE slab layout (R12/R16-verified): slab (8KB) element ((w*2+tt)*64+lane)*8+ke.
__global__ void pack_all_kernel(const float* __restrict__ w1a, const float* __restrict__ w2a,
                                const float* __restrict__ w1b, const float* __restrict__ w2b,
                                unsigned short* __restrict__ o1a, unsigned short* __restrict__ o2a,
                                unsigned short* __restrict__ o1b, unsigned short* __restrict__ o2b) {
  int sel = blockIdx.x >> 9;
  int o = (blockIdx.x & 511) * 256 + threadIdx.x;  // 131072 per matrix
  int ke = o & 7, lane = (o >> 3) & 63, tt = (o >> 9) & 1, w = (o >> 10) & 3, sl = o >> 12;
  int l15 = lane & 15, lg = lane >> 4;
  if (sel == 0 || sel == 2) {
    const float* in = (sel == 0) ? w1a : w1b;
    unsigned short* out = (sel == 0) ? o1a : o1b;
    int h = sl >> 3, kk = sl & 7;
    int n1 = h * 128 + w * 32 + tt * 16 + l15;
    int k = kk * 32 + lg * 8 + ke;
    out[o] = f2b(in[k * 512 + n1]);
  } else {
    const float* in = (sel == 1) ? w2a : w2b;
    unsigned short* out = (sel == 1) ? o2a : o2b;
    int h = sl >> 3, q = sl & 7, h2 = q >> 2, kk2 = q & 3;
    int n2 = h2 * 128 + w * 32 + tt * 16 + l15;
    int k2 = h * 128 + kk2 * 32 + lg * 8 + ke;
    out[o] = f2b(in[k2 * 256 + n2]);
  }
}

// ---------------- fused prep: graph counts + both degree arrays (one launch over A) ----
__global__ void prep_kernel(const int* __restrict__ node_gid, const int* __restrict__ bond_gid,
                            const int* __restrict__ ab_dst, const int* __restrict__ ba_dst,
                            int* cnt_node, int* cnt_bond, int* deg_n, int* deg_e,
                            int N, int E, int A) {
  int i = blockIdx.x * 256 + threadIdx.x;
  if (i < N) atomicAdd(&cnt_node[node_gid[i]], 1);
  if (i < E) {
    atomicAdd(&cnt_bond[bond_gid[i]], 1);
    atomicAdd(&deg_n[ab_dst[i]], 1);
  }
  if (i < A) atomicAdd(&deg_e[ba_dst[i]], 1);
}

// ---------------- CSR scans, both graphs in one grid ----------------
__global__ void scan1_both_kernel(const int* __restrict__ degE, const int* __restrict__ degN,
                                  int* __restrict__ offE, int* __restrict__ offN,
                                  int* __restrict__ bsum, int E, int N, int nbE) {
  int b = blockIdx.x;
  const int* deg; int* excl; int* bs; int n; int bb;
  if (b < nbE) { deg = degE; excl = offE; bs = bsum; n = E; bb = b; }
  else { deg = degN; excl = offN; bs = bsum + 512; n = N; bb = b - nbE; }
  int t = threadIdx.x;
  int i = bb * 256 + t;
  int v = (i < n) ? deg[i] : 0;
  int lane = t & 63, w = t >> 6;
  int s = v;
#pragma unroll
  for (int d = 1; d < 64; d <<= 1) {
    int u = __shfl_up(s, d);
    if (lane >= d) s += u;
  }
  __shared__ int wsum[4];
  if (lane == 63) wsum[w] = s;
  __syncthreads();
  int base = 0;
  for (int ww = 0; ww < w; ++ww) base += wsum[ww];
  if (i < n) excl[i] = base + s - v;
  if (t == 255) bs[bb] = base + s;
}

__global__ void scan2_both_kernel(int* __restrict__ bsum, int nbE, int nbN) {
  int* bs = bsum + blockIdx.x * 512;
  int nb = (blockIdx.x == 0) ? nbE : nbN;
  int t = threadIdx.x;  // 1024 threads
  int v = (t < nb) ? bs[t] : 0;
  int lane = t & 63, w = t >> 6;
  int s = v;
#pragma unroll
  for (int d = 1; d < 64; d <<= 1) {
    int u = __shfl_up(s, d);
    if (lane >= d) s += u;
  }
  __shared__ int wsum[16];
  if (lane == 63) wsum[w] = s;
  __syncthreads();
  int base = 0;
  for (int ww = 0; ww < w; ++ww) base += wsum[ww];
  if (t < nb) bs[t] = base + s - v;
}

// scan3 for both graphs + per-graph factors folded into the tail blocks
__global__ void scan3f_kernel(int* __restrict__ offE, int* __restrict__ offN,
                              const int* __restrict__ bsum,
                              const int* __restrict__ cnt_node, const int* __restrict__ cnt_bond,
                              float* fac_node, float* fac_bond, float* recip_node,
                              int E, int N, int G, int nbE, int nbN) {
  int b = blockIdx.x;
  if (b < nbE) {
    int i = b * 256 + threadIdx.x;
    if (i < E) offE[i] += bsum[b];
  } else if (b < nbE + nbN) {
    int bb = b - nbE;
    int i = bb * 256 + threadIdx.x;
    if (i < N) offN[i] += bsum[512 + bb];
  } else {
    int g = (b - nbE - nbN) * 256 + threadIdx.x;
    if (g < G) {
      float cn = fmaxf((float)cnt_node[g], 1.f);
      float cb = fmaxf((float)cnt_bond[g], 1.f);
      fac_node[g] = rsqrtf(cn);
      fac_bond[g] = rsqrtf(cb);
      recip_node[g] = 1.f / cn;
    }
  }
}

__global__ void fill_both_kernel(const int* __restrict__ ba_dst, const int* __restrict__ ab_dst,
                                 const int* __restrict__ offE, const int* __restrict__ offN,
                                 int* __restrict__ curE, int* __restrict__ curN,
                                 int* __restrict__ csrE, int* __restrict__ csrN,
                                 int A, int E, int nbA) {
  int b = blockIdx.x;
  if (b < nbA) {
    int i = b * 256 + threadIdx.x;
    if (i < A) {
      int d = ba_dst[i];
      int p = atomicAdd(&curE[d], 1);
      csrE[offE[d] + p] = i;
    }
  } else {
    int i = (b - nbA) * 256 + threadIdx.x;
    if (i < E) {
      int d = ab_dst[i];
      int p = atomicAdd(&curN[d], 1);
      csrN[offN[d] + p] = i;
    }
  }
}

// ---------------- gather: agg_e[d] = (Σ rbf_a)@W + cnt·b + Σ edge_hidden[src_a] ----------
// R24-verified: 4 rows/wave hoisted gathers + shared projection.
__global__ __launch_bounds__(256) void angle_gather_kernel(
    const float* __restrict__ bond_angle, const int* __restrict__ ba_src,
    const float* __restrict__ edge_hidden,
    const int* __restrict__ off, const int* __restrict__ deg, const int* __restrict__ csr,
    const float* __restrict__ rbf_w, const float* __restrict__ rbf_b,
    float* __restrict__ agg_e, int E) {
  __shared__ float rbfw_s[32 * 256];  // 32KB
  int t = threadIdx.x;
  int w = t >> 6, lane = t & 63;
#pragma unroll
  for (int i = 0; i < 8; ++i)
    *(f32x4*)&rbfw_s[(t + i * 256) * 4] = *(const f32x4*)&rbf_w[(t + i * 256) * 4];
  __syncthreads();
  int c4 = lane * 4;
  f32x4 bv = *(const f32x4*)&rbf_b[c4];
  float cc = 0.1f * (float)(lane & 31);
  int d0 = blockIdx.x * 16 + w * 4;

  f32x4 ac[4];
  float rb[4];
  int st[4], ct[4];
#pragma unroll
  for (int r = 0; r < 4; ++r) {
    ac[r] = (f32x4)0.f;
    rb[r] = 0.f;
    int d = d0 + r;
    bool vld = d < E;
    st[r] = vld ? off[d] : 0;
    ct[r] = vld ? deg[d] : 0;
  }
  int mx01 = ct[0] > ct[1] ? ct[0] : ct[1];
  int mx23 = ct[2] > ct[3] ? ct[2] : ct[3];
  int mx = mx01 > mx23 ? mx01 : mx23;

  if (mx <= 64) {
    float av[4];
    int ss[4];
#pragma unroll
    for (int r = 0; r < 4; ++r) {
      av[r] = 0.f;
      ss[r] = 0;
      if (lane < ct[r]) {
        int a = csr[st[r] + lane];
        av[r] = bond_angle[a];
        ss[r] = ba_src[a];
      }
    }
#pragma unroll
    for (int r = 0; r < 4; ++r) {
      int n = ct[r];
      for (int i = 0; i < n; ++i) {
        float avi = __shfl(av[r], i);
        int si = __shfl(ss[r], i);
        if (lane < 32) {
          float dd = avi - cc;
          rb[r] += __expf(-10.f * dd * dd);
        }
        ac[r] += *(const f32x4*)&edge_hidden[(size_t)si * HDIM + c4];
      }
    }
  } else {
#pragma unroll
    for (int r = 0; r < 4; ++r) {
      for (int base = 0; base < ct[r]; base += 64) {
        int n = ct[r] - base;
        if (n > 64) n = 64;
        float av = 0.f;
        int s = 0;
        if (lane < n) {
          int a = csr[st[r] + base + lane];
          av = bond_angle[a];
          s = ba_src[a];
        }
        for (int i = 0; i < n; ++i) {
          float avi = __shfl(av, i);
          int si = __shfl(s, i);
          if (lane < 32) {
            float dd = avi - cc;
            rb[r] += __expf(-10.f * dd * dd);
          }
          ac[r] += *(const f32x4*)&edge_hidden[(size_t)si * HDIM + c4];
        }
      }
    }
  }

  // shared projection: one wv read feeds all 4 rows
#pragma unroll 8
  for (int k = 0; k < 32; ++k) {
    f32x4 wv = *(const f32x4*)&rbfw_s[k * 256 + c4];
    f32x4 r0 = (f32x4)__shfl(rb[0], k);
    f32x4 r1 = (f32x4)__shfl(rb[1], k);
    f32x4 r2 = (f32x4)__shfl(rb[2], k);
    f32x4 r3 = (f32x4)__shfl(rb[3], k);
    ac[0] += r0 * wv;
    ac[1] += r1 * wv;
    ac[2] += r2 * wv;
    ac[3] += r3 * wv;
  }

  // bias + store
#pragma unroll
  for (int r = 0; r < 4; ++r) {
    int d = d0 + r;
    if (d < E) {
      f32x4 o = ac[r] + (f32x4)(float)ct[r] * bv;
      *(f32x4*)&agg_e[(size_t)d * HDIM + c4] = o;
    }
  }
}

// ---------------- gather: agg_n[d] = Σ (edge_out[e] + node_hidden[src_e]) --------------
// RESTRUCTURED like angle_gather (R24-verified pattern): 4 rows per wave with HOISTED
// independent index chains (4x memory-level parallelism). Fast path all degrees <= 64
// (mean degree E/N = 2); chunked fallback preserves correctness for any degree.
__global__ __launch_bounds__(256) void node_gather_kernel(
    const float* __restrict__ node_hidden, const float* __restrict__ edge_out,
    const int* __restrict__ ab_src,
    const int* __restrict__ off, const int* __restrict__ deg, const int* __restrict__ csr,
    float* __restrict__ agg_n, int N) {
  int t = threadIdx.x;
  int w = t >> 6, lane = t & 63;
  int c4 = lane * 4;
  int d0 = blockIdx.x * 16 + w * 4;

  f32x4 ac[4];
  int st[4], ct[4];
#pragma unroll
  for (int r = 0; r < 4; ++r) {
    ac[r] = (f32x4)0.f;
    int d = d0 + r;
    bool vld = d < N;
    st[r] = vld ? off[d] : 0;
    ct[r] = vld ? deg[d] : 0;
  }
  int mx01 = ct[0] > ct[1] ? ct[0] : ct[1];
  int mx23 = ct[2] > ct[3] ? ct[2] : ct[3];
  int mx = mx01 > mx23 ? mx01 : mx23;

  if (mx <= 64) {
    // fast path: all 4 rows' index chains issued back-to-back (independent)
    int ee[4], ss[4];
#pragma unroll
    for (int r = 0; r < 4; ++r) {
      ee[r] = 0;
      ss[r] = 0;
      if (lane < ct[r]) {
        int e = csr[st[r] + lane];
        ee[r] = e;
        ss[r] = ab_src[e];
      }
    }
#pragma unroll
    for (int r = 0; r < 4; ++r) {
      int n = ct[r];
      for (int i = 0; i < n; ++i) {
        int ei = __shfl(ee[r], i);
        int si = __shfl(ss[r], i);
        f32x4 a = *(const f32x4*)&edge_out[(size_t)ei * HDIM + c4];
        f32x4 b = *(const f32x4*)&node_hidden[(size_t)si * HDIM + c4];
        ac[r] += a;
        ac[r] += b;
      }
    }
  } else {
    // slow path: chunked per row (rare; correctness for any degree)
#pragma unroll
    for (int r = 0; r < 4; ++r) {
      for (int base = 0; base < ct[r]; base += 64) {
        int n = ct[r] - base;
        if (n > 64) n = 64;
        int e = 0, s = 0;
        if (lane < n) {
          e = csr[st[r] + base + lane];
          s = ab_src[e];
        }
        for (int i = 0; i < n; ++i) {
          int ei = __shfl(e, i);
          int si = __shfl(s, i);
          f32x4 a = *(const f32x4*)&edge_out[(size_t)ei * HDIM + c4];
          f32x4 b = *(const f32x4*)&node_hidden[(size_t)si * HDIM + c4];
          ac[r] += a;
          ac[r] += b;
        }
      }
    }
  }

#pragma unroll
  for (int r = 0; r < 4; ++r) {
    int d = d0 + r;
    if (d < N) *(f32x4*)&agg_n[(size_t)d * HDIM + c4] = ac[r];
  }
}

// ---------------- fused MLP + LayerNorm + graph_normal + residual (+pool) ----------------
// R23-verified best mlp: barrier-free direct-L2 weights, distance-2 named-register
// prefetch, register finalize, T5 s_setprio around MFMA clusters.
template <int POOL>
__global__ __launch_bounds__(256, 4) void mlp_kernel(
    const float* agg_in, float* out_rows,  // may alias (in-place per-block)
    const float* __restrict__ residual, const int* __restrict__ gid,
    const float* __restrict__ gfactor, const float* __restrict__ grecip,
    const unsigned short* __restrict__ w1p, const float* __restrict__ b1,
    const unsigned short* __restrict__ w2p, const float* __restrict__ b2,
    const float* __restrict__ ln_g, const float* __restrict__ ln_b,
    float* pool_out, int M) {
  __shared__ __align__(16) char smem[26368];
  char* Xb = smem;                        // bf16 [32][256] swizzled, 16KB
  char* Hb = smem + 16384;                // bf16 [32][128] quarter, swizzled, 8KB
  float* psA = (float*)(smem + 24576);    // [32][4]
  float* psB = (float*)(smem + 25088);    // [32][4]
  float* fstat = (float*)(smem + 25600);  // [32][2]
  float* gfs = (float*)(smem + 25856);    // [32]
  float* grs = (float*)(smem + 25984);    // [32] recip (POOL)
  int* gid_s = (int*)(smem + 26112);      // [32]

  int t = threadIdx.x;
  int row0 = blockIdx.x * 32;
  int w = t >> 6, lane = t & 63;
  int l15 = lane & 15, lg = lane >> 4;

  const unsigned short* w1f = w1p + ((size_t)(w * 2) * 64 + lane) * 8;
  const unsigned short* w2f = w2p + ((size_t)(w * 2) * 64 + lane) * 8;
#define W1F(hh, kk, tt) (*(const bf16x8*)(w1f + (size_t)((hh) * 8 + (kk)) * 4096 + (tt) * 512))
#define W2F(hh, q, nf) (*(const bf16x8*)(w2f + (size_t)((hh) * 8 + (q)) * 4096 + (nf) * 512))

  bf16x8 wcur0, wcur1, wmid0, wmid1, wnxt0, wnxt1;
  wcur0 = W1F(0, 0, 0);
  wcur1 = W1F(0, 0, 1);
  wmid0 = W1F(0, 1, 0);
  wmid1 = W1F(0, 1, 1);

  // ---- prologue: stage X (f32 -> bf16 swizzled); graph tables ----
  {
    int row = t >> 3;
    int c0 = (t & 7) * 32;
    int gr = row0 + row; if (gr >= M) gr = M - 1;
    const float* src = agg_in + (size_t)gr * HDIM + c0;
#pragma unroll
    for (int i = 0; i < 4; ++i) {
      f32x4 a = *(const f32x4*)(src + i * 8);
      f32x4 b = *(const f32x4*)(src + i * 8 + 4);
      int byte = (row * 512 + (c0 + i * 8) * 2) ^ ((row & 7) << 4);
      *(uint4*)(Xb + byte) =
          make_uint4(pk2(a[0], a[1]), pk2(a[2], a[3]), pk2(b[0], b[1]), pk2(b[2], b[3]));
    }
    if (t < 32) {
      int r = row0 + t;
      int g = (r < M) ? gid[r] : 0;
      gid_s[t] = g;
      gfs[t] = gfactor[g];
      if (POOL) grs[t] = grecip[g];
    }
  }
  __syncthreads();

  f32x4 acc2[2][4];  // [mt][h2*2+nf] : row = mt*16+lg*4+jr ; col = h2*128+w*32+nf*16+l15
#pragma unroll
  for (int mt = 0; mt < 2; ++mt)
#pragma unroll
    for (int nf = 0; nf < 4; ++nf) acc2[mt][nf] = (f32x4)0.f;

  for (int h = 0; h < 4; ++h) {
    f32x4 acc1[2][2];  // [tt][mt]
#pragma unroll
    for (int tt = 0; tt < 2; ++tt)
#pragma unroll
      for (int mt = 0; mt < 2; ++mt) acc1[tt][mt] = (f32x4)0.f;

    // ---- GEMM1 quarter: no barriers; weights direct from L2, distance-2 prefetch ----
#pragma unroll
    for (int kk = 0; kk < 8; ++kk) {
      if (kk < 6) {
        wnxt0 = W1F(h, kk + 2, 0);
        wnxt1 = W1F(h, kk + 2, 1);
      } else {
        wnxt0 = W2F(h, kk - 6, 0);
        wnxt1 = W2F(h, kk - 6, 1);
      }
      bf16x8 xfr0, xfr1;
      {
        int byte0 = (l15 * 512 + kk * 64 + lg * 16) ^ ((l15 & 7) << 4);
        xfr0 = *(const bf16x8*)(Xb + byte0);
        int m = 16 + l15;
        int byte1 = (m * 512 + kk * 64 + lg * 16) ^ ((m & 7) << 4);
        xfr1 = *(const bf16x8*)(Xb + byte1);
      }
      __builtin_amdgcn_s_setprio(1);
      acc1[0][0] = __builtin_amdgcn_mfma_f32_16x16x32_bf16(wcur0, xfr0, acc1[0][0], 0, 0, 0);
      acc1[0][1] = __builtin_amdgcn_mfma_f32_16x16x32_bf16(wcur0, xfr1, acc1[0][1], 0, 0, 0);
      acc1[1][0] = __builtin_amdgcn_mfma_f32_16x16x32_bf16(wcur1, xfr0, acc1[1][0], 0, 0, 0);
      acc1[1][1] = __builtin_amdgcn_mfma_f32_16x16x32_bf16(wcur1, xfr1, acc1[1][1], 0, 0, 0);
      __builtin_amdgcn_s_setprio(0);
      wcur0 = wmid0; wcur1 = wmid1;
      wmid0 = wnxt0; wmid1 = wnxt1;
    }

    // ---- bias + relu + packed Hb store ----
#pragma unroll
    for (int tt = 0; tt < 2; ++tt) {
      f32x4 b1v = *(const f32x4*)&b1[h * 128 + w * 32 + tt * 16 + lg * 4];
#pragma unroll
      for (int mt = 0; mt < 2; ++mt) {
        f32x4 v = acc1[tt][mt] + b1v;
        v[0] = fmaxf(v[0], 0.f); v[1] = fmaxf(v[1], 0.f);
        v[2] = fmaxf(v[2], 0.f); v[3] = fmaxf(v[3], 0.f);
        int m = mt * 16 + l15;
        int n1l = w * 32 + tt * 16 + lg * 4;
        int byte = (m * 256 + n1l * 2) ^ ((m & 7) << 4);
        *(uint2*)(Hb + byte) = make_uint2(pk2(v[0], v[1]), pk2(v[2], v[3]));
      }
    }
    __syncthreads();  // Hb ready for all waves

    // ---- GEMM2 quarter: no barriers; weights direct from L2, distance-2 prefetch ----
#pragma unroll
    for (int q = 0; q < 8; ++q) {
      if (q < 6) {
        wnxt0 = W2F(h, q + 2, 0);
        wnxt1 = W2F(h, q + 2, 1);
      } else if (h < 3) {
        wnxt0 = W1F(h + 1, q - 6, 0);
        wnxt1 = W1F(h + 1, q - 6, 1);
      }
      int kk2 = q & 3, h2 = q >> 2;
      bf16x8 hfr0, hfr1;
      {
        int byte0 = (l15 * 256 + kk2 * 64 + lg * 16) ^ ((l15 & 7) << 4);
        hfr0 = *(const bf16x8*)(Hb + byte0);
        int m = 16 + l15;
        int byte1 = (m * 256 + kk2 * 64 + lg * 16) ^ ((m & 7) << 4);
        hfr1 = *(const bf16x8*)(Hb + byte1);
      }
      __builtin_amdgcn_s_setprio(1);
      acc2[0][h2 * 2 + 0] = __builtin_amdgcn_mfma_f32_16x16x32_bf16(hfr0, wcur0, acc2[0][h2 * 2 + 0], 0, 0, 0);
      acc2[0][h2 * 2 + 1] = __builtin_amdgcn_mfma_f32_16x16x32_bf16(hfr0, wcur1, acc2[0][h2 * 2 + 1], 0, 0, 0);
      acc2[1][h2 * 2 + 0] = __builtin_amdgcn_mfma_f32_16x16x32_bf16(hfr1, wcur0, acc2[1][h2 * 2 + 0], 0, 0, 0);
      acc2[1][h2 * 2 + 1] = __builtin_amdgcn_mfma_f32_16x16x32_bf16(hfr1, wcur1, acc2[1][h2 * 2 + 1], 0, 0, 0);
      __builtin_amdgcn_s_setprio(0);
      wcur0 = wmid0; wcur1 = wmid1;
      wmid0 = wnxt0; wmid1 = wnxt1;
    }
    __syncthreads();  // all waves done reading Hb before next h overwrites
  }
#undef W1F
#undef W2F

  // ---- row stats straight from acc2 registers ----
  {
#pragma unroll
    for (int mt = 0; mt < 2; ++mt)
#pragma unroll
      for (int jr = 0; jr < 4; ++jr) {
        float sv = 0.f, ssv = 0.f;
#pragma unroll
        for (int nfi = 0; nfi < 4; ++nfi) {
          int col = (nfi >> 1) * 128 + w * 32 + (nfi & 1) * 16 + l15;
          float v = acc2[mt][nfi][jr] + b2[col];
          sv += v;
          ssv += v * v;
        }
        sv += __shfl_xor(sv, 1); ssv += __shfl_xor(ssv, 1);
        sv += __shfl_xor(sv, 2); ssv += __shfl_xor(ssv, 2);
        sv += __shfl_xor(sv, 4); ssv += __shfl_xor(ssv, 4);
        sv += __shfl_xor(sv, 8); ssv += __shfl_xor(ssv, 8);
        if (l15 == 0) {
          int r = mt * 16 + lg * 4 + jr;
          psA[r * 4 + w] = sv;
          psB[r * 4 + w] = ssv;
        }
      }
  }
  __syncthreads();
  if (t < 32) {
    float sv = psA[t * 4] + psA[t * 4 + 1] + psA[t * 4 + 2] + psA[t * 4 + 3];
    float ssv = psB[t * 4] + psB[t * 4 + 1] + psB[t * 4 + 2] + psB[t * 4 + 3];
    float mean = sv * (1.f / 256.f);
    float var = ssv * (1.f / 256.f) - mean * mean;
    fstat[t * 2] = mean;
    fstat[t * 2 + 1] = rsqrtf(var + LNEPS);
  }
  __syncthreads();

  // ---- finalize straight from acc2: LN affine, graph_normal, residual, store (+pool) ----
  {
    int c0 = w * 32 + l15, c1 = c0 + 16, c2 = c0 + 128, c3 = c0 + 144;
    float b2v0 = b2[c0], b2v1 = b2[c1], b2v2 = b2[c2], b2v3 = b2[c3];
    float lgm0 = ln_g[c0], lgm1 = ln_g[c1], lgm2 = ln_g[c2], lgm3 = ln_g[c3];
    float lbm0 = ln_b[c0], lbm1 = ln_b[c1], lbm2 = ln_b[c2], lbm3 = ln_b[c3];
    float p0 = 0.f, p1 = 0.f, p2 = 0.f, p3 = 0.f;
    float crec = 0.f;
    int curg = -1;
#pragma unroll
    for (int mt = 0; mt < 2; ++mt) {
#pragma unroll
      for (int jr = 0; jr < 4; ++jr) {
        int r = mt * 16 + lg * 4 + jr;
        int gr = row0 + r;
        if (gr < M) {
          float mean = fstat[r * 2], rstd = fstat[r * 2 + 1];
          float gf = gfs[r];
          if (POOL) {
            int g = gid_s[r];
            if (g != curg) {
              if (curg >= 0) {
                atomicAdd(&pool_out[(size_t)curg * HDIM + c0], p0 * crec);
                atomicAdd(&pool_out[(size_t)curg * HDIM + c1], p1 * crec);
                atomicAdd(&pool_out[(size_t)curg * HDIM + c2], p2 * crec);
                atomicAdd(&pool_out[(size_t)curg * HDIM + c3], p3 * crec);
              }
              curg = g; crec = grs[r];
              p0 = 0.f; p1 = 0.f; p2 = 0.f; p3 = 0.f;
            }
          }
          const float* resp = residual + (size_t)gr * HDIM;
          float* outp = out_rows + (size_t)gr * HDIM;
          float v0 = ((acc2[mt][0][jr] + b2v0 - mean) * rstd * lgm0 + lbm0) * gf + resp[c0];
          float v1 = ((acc2[mt][1][jr] + b2v1 - mean) * rstd * lgm1 + lbm1) * gf + resp[c1];
          float v2 = ((acc2[mt][2][jr] + b2v2 - mean) * rstd * lgm2 + lbm2) * gf + resp[c2];
          float v3 = ((acc2[mt][3][jr] + b2v3 - mean) * rstd * lgm3 + lbm3) * gf + resp[c3];
          outp[c0] = v0; outp[c1] = v1; outp[c2] = v2; outp[c3] = v3;
          if (POOL) { p0 += v0; p1 += v1; p2 += v2; p3 += v3; }
        }
      }
    }
    if (POOL && curg >= 0) {
      atomicAdd(&pool_out[(size_t)curg * HDIM + c0], p0 * crec);
      atomicAdd(&pool_out[(size_t)curg * HDIM + c1], p1 * crec);
      atomicAdd(&pool_out[(size_t)curg * HDIM + c2], p2 * crec);
      atomicAdd(&pool_out[(size_t)curg * HDIM + c3], p3 * crec);
    }
  }
}

extern "C" void kernel_launch(void* const* d_in, const int* in_sizes, int n_in,
                              void* d_out, int out_size, void* d_ws, size_t ws_size,
                              hipStream_t stream) {
  const float* node_hidden = (const float*)d_in[0];
  const float* edge_hidden = (const float*)d_in[1];
  const float* bond_angle = (const float*)d_in[2];
  const int* ab_src = (const int*)d_in[3];
  const int* ab_dst = (const int*)d_in[4];
  const int* ba_src = (const int*)d_in[5];
  const int* ba_dst = (const int*)d_in[6];
  const int* node_gid = (const int*)d_in[7];
  const int* bond_gid = (const int*)d_in[8];
  const float* rbf_w = (const float*)d_in[10];
  const float* rbf_b = (const float*)d_in[11];
  const float* ba_w1 = (const float*)d_in[12];
  const float* ba_b1 = (const float*)d_in[13];
  const float* ba_w2 = (const float*)d_in[14];
  const float* ba_b2 = (const float*)d_in[15];
  const float* ba_ln_g = (const float*)d_in[16];
  const float* ba_ln_b = (const float*)d_in[17];
  const float* ab_w1 = (const float*)d_in[18];
  const float* ab_b1 = (const float*)d_in[19];
  const float* ab_w2 = (const float*)d_in[20];
  const float* ab_b2 = (const float*)d_in[21];
  const float* ab_ln_g = (const float*)d_in[22];
  const float* ab_ln_b = (const float*)d_in[23];

  int N = in_sizes[0] / HDIM;
  int E = in_sizes[1] / HDIM;
  int A = in_sizes[2];
  int G = out_size / HDIM - N - E;

  float* out_node = (float*)d_out;
  float* out_edge = out_node + (size_t)N * HDIM;
  float* out_graph = out_edge + (size_t)E * HDIM;

  // ---- workspace layout ----
  char* ws = (char*)d_ws;
  int* cnt_node = (int*)ws;                    // G   (zeroed)
  int* cnt_bond = cnt_node + G;                // G   (zeroed)
  int* deg_e = cnt_bond + G;                   // E   (zeroed)
  int* cur_e = deg_e + E;                      // E   (zeroed)
  int* deg_n = cur_e + E;                      // N   (zeroed)
  int* cur_n = deg_n + N;                      // N   (zeroed)
  size_t zero_bytes = (size_t)(2 * G + 2 * E + 2 * N) * 4;
  float* fac_node = (float*)(cur_n + N);       // G
  float* fac_bond = fac_node + G;              // G
  float* recip_node = fac_bond + G;            // G
  int* off_e = (int*)(recip_node + G);         // E
  int* csr_e = off_e + E;                      // A
  int* off_n = csr_e + A;                      // N
  int* csr_n = off_n + N;                      // E
  int* bsum = csr_n + E;                       // 1024 (E-part [0,512), N-part [512,768))
  size_t off = ((size_t)((char*)(bsum + 1024) - ws) + 255) & ~(size_t)255;
  unsigned short* w1p_ba = (unsigned short*)(ws + off); off += (size_t)512 * 256 * 2;
  unsigned short* w2p_ba = (unsigned short*)(ws + off); off += (size_t)256 * 512 * 2;
  unsigned short* w1p_ab = (unsigned short*)(ws + off); off += (size_t)512 * 256 * 2;
  unsigned short* w2p_ab = (unsigned short*)(ws + off); off += (size_t)256 * 512 * 2;

  hipMemsetAsync(d_ws, 0, zero_bytes, stream);
  hipMemsetAsync(out_graph, 0, (size_t)G * HDIM * 4, stream);

  pack_all_kernel<<<2048, 256, 0, stream>>>(ba_w1, ba_w2, ab_w1, ab_w2,
                                            w1p_ba, w2p_ba, w1p_ab, w2p_ab);

  prep_kernel<<<(A + 255) / 256, 256, 0, stream>>>(node_gid, bond_gid, ab_dst, ba_dst,
                                                   cnt_node, cnt_bond, deg_n, deg_e, N, E, A);

  int nbE = (E + 255) / 256;
  int nbN = (N + 255) / 256;
  int nbA = (A + 255) / 256;
  int nbG = (G + 255) / 256;
  scan1_both_kernel<<<nbE + nbN, 256, 0, stream>>>(deg_e, deg_n, off_e, off_n, bsum, E, N, nbE);
  scan2_both_kernel<<<2, 1024, 0, stream>>>(bsum, nbE, nbN);
  scan3f_kernel<<<nbE + nbN + nbG, 256, 0, stream>>>(off_e, off_n, bsum, cnt_node, cnt_bond,
                                                     fac_node, fac_bond, recip_node,
                                                     E, N, G, nbE, nbN);
  fill_both_kernel<<<nbA + nbE, 256, 0, stream>>>(ba_dst, ab_dst, off_e, off_n,
                                                  cur_e, cur_n, csr_e, csr_n, A, E, nbA);

  angle_gather_kernel<<<(E + 15) / 16, 256, 0, stream>>>(bond_angle, ba_src, edge_hidden,
                                                         off_e, deg_e, csr_e, rbf_w, rbf_b,
                                                         out_edge, E);
  mlp_kernel<0><<<(E + 31) / 32, 256, 0, stream>>>(out_edge, out_edge, edge_hidden, bond_gid,
                                                   fac_bond, nullptr, w1p_ba, ba_b1, w2p_ba,
                                                   ba_b2, ba_ln_g, ba_ln_b, nullptr, E);

  node_gather_kernel<<<(N + 15) / 16, 256, 0, stream>>>(node_hidden, out_edge, ab_src,
                                                        off_n, deg_n, csr_n, out_node, N);
  mlp_kernel<1><<<(N + 31) / 32, 256, 0, stream>>>(out_node, out_node, node_hidden, node_gid,
                                                   fac_node, recip_node, w1p_ab, ab_b1, w2p_ab,
                                                   ab_b2, ab_ln_g, ab_ln_b, out_graph, N);
}

// Round 26
// 503.446 us; speedup vs baseline: 1.0138x; 1.0138x over previous
//
#include <hip/hip_runtime.h>

#define HDIM 256
#define LNEPS 1e-5f

typedef float f32x4 __attribute__((ext_vector_type(4)));
typedef short bf16x8 __attribute__((ext_vector_type(8)));

static __device__ __forceinline__ unsigned short f2b(float f) {
  union { float f; unsigned u; } v; v.f = f;
  return (unsigned short)((v.u + 0x7fffu + ((v.u >> 16) & 1u)) >> 16);
}
static __device__ __forceinline__ unsigned pk2(float lo, float hi) {
  return (unsigned)f2b(lo) | ((unsigned)f2b(hi) << 16);
}

// ---------------- weight repack (all 4 matrices, one launch) ----------------
// WAVE-PRIVATE slab layout (R12/R16-verified): slab (8KB) element ((w*2+tt)*64+lane)*8+ke.
__global__ void pack_all_kernel(const float* __restrict__ w1a, const float* __restrict__ w2a,
                                const float* __restrict__ w1b, const float* __restrict__ w2b,
                                unsigned short* __restrict__ o1a, unsigned short* __restrict__ o2a,
                                unsigned short* __restrict__ o1b, unsigned short* __restrict__ o2b) {
  int sel = blockIdx.x >> 9;
  int o = (blockIdx.x & 511) * 256 + threadIdx.x;  // 131072 per matrix
  int ke = o & 7, lane = (o >> 3) & 63, tt = (o >> 9) & 1, w = (o >> 10) & 3, sl = o >> 12;
  int l15 = lane & 15, lg = lane >> 4;
  if (sel == 0 || sel == 2) {
    const float* in = (sel == 0) ? w1a : w1b;
    unsigned short* out = (sel == 0) ? o1a : o1b;
    int h = sl >> 3, kk = sl & 7;
    int n1 = h * 128 + w * 32 + tt * 16 + l15;
    int k = kk * 32 + lg * 8 + ke;
    out[o] = f2b(in[k * 512 + n1]);
  } else {
    const float* in = (sel == 1) ? w2a : w2b;
    unsigned short* out = (sel == 1) ? o2a : o2b;
    int h = sl >> 3, q = sl & 7, h2 = q >> 2, kk2 = q & 3;
    int n2 = h2 * 128 + w * 32 + tt * 16 + l15;
    int k2 = h * 128 + kk2 * 32 + lg * 8 + ke;
    out[o] = f2b(in[k2 * 256 + n2]);
  }
}

// ---------------- fused prep: graph counts + both degree arrays (one launch over A) ----
__global__ void prep_kernel(const int* __restrict__ node_gid, const int* __restrict__ bond_gid,
                            const int* __restrict__ ab_dst, const int* __restrict__ ba_dst,
                            int* cnt_node, int* cnt_bond, int* deg_n, int* deg_e,
                            int N, int E, int A) {
  int i = blockIdx.x * 256 + threadIdx.x;
  if (i < N) atomicAdd(&cnt_node[node_gid[i]], 1);
  if (i < E) {
    atomicAdd(&cnt_bond[bond_gid[i]], 1);
    atomicAdd(&deg_n[ab_dst[i]], 1);
  }
  if (i < A) atomicAdd(&deg_e[ba_dst[i]], 1);
}

// ---------------- CSR scans, both graphs in one grid ----------------
__global__ void scan1_both_kernel(const int* __restrict__ degE, const int* __restrict__ degN,
                                  int* __restrict__ offE, int* __restrict__ offN,
                                  int* __restrict__ bsum, int E, int N, int nbE) {
  int b = blockIdx.x;
  const int* deg; int* excl; int* bs; int n; int bb;
  if (b < nbE) { deg = degE; excl = offE; bs = bsum; n = E; bb = b; }
  else { deg = degN; excl = offN; bs = bsum + 512; n = N; bb = b - nbE; }
  int t = threadIdx.x;
  int i = bb * 256 + t;
  int v = (i < n) ? deg[i] : 0;
  int lane = t & 63, w = t >> 6;
  int s = v;
#pragma unroll
  for (int d = 1; d < 64; d <<= 1) {
    int u = __shfl_up(s, d);
    if (lane >= d) s += u;
  }
  __shared__ int wsum[4];
  if (lane == 63) wsum[w] = s;
  __syncthreads();
  int base = 0;
  for (int ww = 0; ww < w; ++ww) base += wsum[ww];
  if (i < n) excl[i] = base + s - v;
  if (t == 255) bs[bb] = base + s;
}

__global__ void scan2_both_kernel(int* __restrict__ bsum, int nbE, int nbN) {
  int* bs = bsum + blockIdx.x * 512;
  int nb = (blockIdx.x == 0) ? nbE : nbN;
  int t = threadIdx.x;  // 1024 threads
  int v = (t < nb) ? bs[t] : 0;
  int lane = t & 63, w = t >> 6;
  int s = v;
#pragma unroll
  for (int d = 1; d < 64; d <<= 1) {
    int u = __shfl_up(s, d);
    if (lane >= d) s += u;
  }
  __shared__ int wsum[16];
  if (lane == 63) wsum[w] = s;
  __syncthreads();
  int base = 0;
  for (int ww = 0; ww < w; ++ww) base += wsum[ww];
  if (t < nb) bs[t] = base + s - v;
}

// scan3 for both graphs + per-graph factors folded into the tail blocks
__global__ void scan3f_kernel(int* __restrict__ offE, int* __restrict__ offN,
                              const int* __restrict__ bsum,
                              const int* __restrict__ cnt_node, const int* __restrict__ cnt_bond,
                              float* fac_node, float* fac_bond, float* recip_node,
                              int E, int N, int G, int nbE, int nbN) {
  int b = blockIdx.x;
  if (b < nbE) {
    int i = b * 256 + threadIdx.x;
    if (i < E) offE[i] += bsum[b];
  } else if (b < nbE + nbN) {
    int bb = b - nbE;
    int i = bb * 256 + threadIdx.x;
    if (i < N) offN[i] += bsum[512 + bb];
  } else {
    int g = (b - nbE - nbN) * 256 + threadIdx.x;
    if (g < G) {
      float cn = fmaxf((float)cnt_node[g], 1.f);
      float cb = fmaxf((float)cnt_bond[g], 1.f);
      fac_node[g] = rsqrtf(cn);
      fac_bond[g] = rsqrtf(cb);
      recip_node[g] = 1.f / cn;
    }
  }
}

__global__ void fill_both_kernel(const int* __restrict__ ba_dst, const int* __restrict__ ab_dst,
                                 const int* __restrict__ offE, const int* __restrict__ offN,
                                 int* __restrict__ curE, int* __restrict__ curN,
                                 int* __restrict__ csrE, int* __restrict__ csrN,
                                 int A, int E, int nbA) {
  int b = blockIdx.x;
  if (b < nbA) {
    int i = b * 256 + threadIdx.x;
    if (i < A) {
      int d = ba_dst[i];
      int p = atomicAdd(&curE[d], 1);
      csrE[offE[d] + p] = i;
    }
  } else {
    int i = (b - nbA) * 256 + threadIdx.x;
    if (i < E) {
      int d = ab_dst[i];
      int p = atomicAdd(&curN[d], 1);
      csrN[offN[d] + p] = i;
    }
  }
}

// ---------------- gather: agg_e[d] = (Σ rbf_a)@W + cnt·b + Σ edge_hidden[src_a] ----------
// R24-verified: 4 rows/wave hoisted gathers + shared projection.
__global__ __launch_bounds__(256) void angle_gather_kernel(
    const float* __restrict__ bond_angle, const int* __restrict__ ba_src,
    const float* __restrict__ edge_hidden,
    const int* __restrict__ off, const int* __restrict__ deg, const int* __restrict__ csr,
    const float* __restrict__ rbf_w, const float* __restrict__ rbf_b,
    float* __restrict__ agg_e, int E) {
  __shared__ float rbfw_s[32 * 256];  // 32KB
  int t = threadIdx.x;
  int w = t >> 6, lane = t & 63;
#pragma unroll
  for (int i = 0; i < 8; ++i)
    *(f32x4*)&rbfw_s[(t + i * 256) * 4] = *(const f32x4*)&rbf_w[(t + i * 256) * 4];
  __syncthreads();
  int c4 = lane * 4;
  f32x4 bv = *(const f32x4*)&rbf_b[c4];
  float cc = 0.1f * (float)(lane & 31);
  int d0 = blockIdx.x * 16 + w * 4;

  f32x4 ac[4];
  float rb[4];
  int st[4], ct[4];
#pragma unroll
  for (int r = 0; r < 4; ++r) {
    ac[r] = (f32x4)0.f;
    rb[r] = 0.f;
    int d = d0 + r;
    bool vld = d < E;
    st[r] = vld ? off[d] : 0;
    ct[r] = vld ? deg[d] : 0;
  }
  int mx01 = ct[0] > ct[1] ? ct[0] : ct[1];
  int mx23 = ct[2] > ct[3] ? ct[2] : ct[3];
  int mx = mx01 > mx23 ? mx01 : mx23;

  if (mx <= 64) {
    float av[4];
    int ss[4];
#pragma unroll
    for (int r = 0; r < 4; ++r) {
      av[r] = 0.f;
      ss[r] = 0;
      if (lane < ct[r]) {
        int a = csr[st[r] + lane];
        av[r] = bond_angle[a];
        ss[r] = ba_src[a];
      }
    }
#pragma unroll
    for (int r = 0; r < 4; ++r) {
      int n = ct[r];
      for (int i = 0; i < n; ++i) {
        float avi = __shfl(av[r], i);
        int si = __shfl(ss[r], i);
        if (lane < 32) {
          float dd = avi - cc;
          rb[r] += __expf(-10.f * dd * dd);
        }
        ac[r] += *(const f32x4*)&edge_hidden[(size_t)si * HDIM + c4];
      }
    }
  } else {
#pragma unroll
    for (int r = 0; r < 4; ++r) {
      for (int base = 0; base < ct[r]; base += 64) {
        int n = ct[r] - base;
        if (n > 64) n = 64;
        float av = 0.f;
        int s = 0;
        if (lane < n) {
          int a = csr[st[r] + base + lane];
          av = bond_angle[a];
          s = ba_src[a];
        }
        for (int i = 0; i < n; ++i) {
          float avi = __shfl(av, i);
          int si = __shfl(s, i);
          if (lane < 32) {
            float dd = avi - cc;
            rb[r] += __expf(-10.f * dd * dd);
          }
          ac[r] += *(const f32x4*)&edge_hidden[(size_t)si * HDIM + c4];
        }
      }
    }
  }

  // shared projection: one wv read feeds all 4 rows
#pragma unroll 8
  for (int k = 0; k < 32; ++k) {
    f32x4 wv = *(const f32x4*)&rbfw_s[k * 256 + c4];
    f32x4 r0 = (f32x4)__shfl(rb[0], k);
    f32x4 r1 = (f32x4)__shfl(rb[1], k);
    f32x4 r2 = (f32x4)__shfl(rb[2], k);
    f32x4 r3 = (f32x4)__shfl(rb[3], k);
    ac[0] += r0 * wv;
    ac[1] += r1 * wv;
    ac[2] += r2 * wv;
    ac[3] += r3 * wv;
  }

  // bias + store
#pragma unroll
  for (int r = 0; r < 4; ++r) {
    int d = d0 + r;
    if (d < E) {
      f32x4 o = ac[r] + (f32x4)(float)ct[r] * bv;
      *(f32x4*)&agg_e[(size_t)d * HDIM + c4] = o;
    }
  }
}

// ---------------- gather: agg_n[d] = Σ (edge_out[e] + node_hidden[src_e]) --------------
// R24-verified variant (1 row per wave; R25's 4-row hoist was null-to-negative here).
__global__ __launch_bounds__(256) void node_gather_kernel(
    const float* __restrict__ node_hidden, const float* __restrict__ edge_out,
    const int* __restrict__ ab_src,
    const int* __restrict__ off, const int* __restrict__ deg, const int* __restrict__ csr,
    float* __restrict__ agg_n, int N) {
  int w = threadIdx.x >> 6, lane = threadIdx.x & 63;
  int d = blockIdx.x * 4 + w;
  if (d >= N) return;
  int c4 = lane * 4;
  int start = off[d], cnt = deg[d];
  f32x4 acc = (f32x4)0.f;
  for (int base = 0; base < cnt; base += 64) {
    int n = cnt - base; if (n > 64) n = 64;
    int e = 0, s = 0;
    if (lane < n) {
      e = csr[start + base + lane];
      s = ab_src[e];
    }
#pragma unroll 4
    for (int i = 0; i < n; ++i) {
      int ei = __shfl(e, i);
      int si = __shfl(s, i);
      f32x4 a = *(const f32x4*)&edge_out[(size_t)ei * HDIM + c4];
      f32x4 b = *(const f32x4*)&node_hidden[(size_t)si * HDIM + c4];
      acc += a;
      acc += b;
    }
  }
  *(f32x4*)&agg_n[(size_t)d * HDIM + c4] = acc;
}

// ---------------- fused MLP + LayerNorm + graph_normal + residual (+pool) ----------------
// R23-verified best mlp: barrier-free direct-L2 weights, distance-2 named-register
// prefetch, register finalize, T5 s_setprio around MFMA clusters.
template <int POOL>
__global__ __launch_bounds__(256, 4) void mlp_kernel(
    const float* agg_in, float* out_rows,  // may alias (in-place per-block)
    const float* __restrict__ residual, const int* __restrict__ gid,
    const float* __restrict__ gfactor, const float* __restrict__ grecip,
    const unsigned short* __restrict__ w1p, const float* __restrict__ b1,
    const unsigned short* __restrict__ w2p, const float* __restrict__ b2,
    const float* __restrict__ ln_g, const float* __restrict__ ln_b,
    float* pool_out, int M) {
  __shared__ __align__(16) char smem[26368];
  char* Xb = smem;                        // bf16 [32][256] swizzled, 16KB
  char* Hb = smem + 16384;                // bf16 [32][128] quarter, swizzled, 8KB
  float* psA = (float*)(smem + 24576);    // [32][4]
  float* psB = (float*)(smem + 25088);    // [32][4]
  float* fstat = (float*)(smem + 25600);  // [32][2]
  float* gfs = (float*)(smem + 25856);    // [32]
  float* grs = (float*)(smem + 25984);    // [32] recip (POOL)
  int* gid_s = (int*)(smem + 26112);      // [32]

  int t = threadIdx.x;
  int row0 = blockIdx.x * 32;
  int w = t >> 6, lane = t & 63;
  int l15 = lane & 15, lg = lane >> 4;

  const unsigned short* w1f = w1p + ((size_t)(w * 2) * 64 + lane) * 8;
  const unsigned short* w2f = w2p + ((size_t)(w * 2) * 64 + lane) * 8;
#define W1F(hh, kk, tt) (*(const bf16x8*)(w1f + (size_t)((hh) * 8 + (kk)) * 4096 + (tt) * 512))
#define W2F(hh, q, nf) (*(const bf16x8*)(w2f + (size_t)((hh) * 8 + (q)) * 4096 + (nf) * 512))

  bf16x8 wcur0, wcur1, wmid0, wmid1, wnxt0, wnxt1;
  wcur0 = W1F(0, 0, 0);
  wcur1 = W1F(0, 0, 1);
  wmid0 = W1F(0, 1, 0);
  wmid1 = W1F(0, 1, 1);

  // ---- prologue: stage X (f32 -> bf16 swizzled); graph tables ----
  {
    int row = t >> 3;
    int c0 = (t & 7) * 32;
    int gr = row0 + row; if (gr >= M) gr = M - 1;
    const float* src = agg_in + (size_t)gr * HDIM + c0;
#pragma unroll
    for (int i = 0; i < 4; ++i) {
      f32x4 a = *(const f32x4*)(src + i * 8);
      f32x4 b = *(const f32x4*)(src + i * 8 + 4);
      int byte = (row * 512 + (c0 + i * 8) * 2) ^ ((row & 7) << 4);
      *(uint4*)(Xb + byte) =
          make_uint4(pk2(a[0], a[1]), pk2(a[2], a[3]), pk2(b[0], b[1]), pk2(b[2], b[3]));
    }
    if (t < 32) {
      int r = row0 + t;
      int g = (r < M) ? gid[r] : 0;
      gid_s[t] = g;
      gfs[t] = gfactor[g];
      if (POOL) grs[t] = grecip[g];
    }
  }
  __syncthreads();

  f32x4 acc2[2][4];  // [mt][h2*2+nf] : row = mt*16+lg*4+jr ; col = h2*128+w*32+nf*16+l15
#pragma unroll
  for (int mt = 0; mt < 2; ++mt)
#pragma unroll
    for (int nf = 0; nf < 4; ++nf) acc2[mt][nf] = (f32x4)0.f;

  for (int h = 0; h < 4; ++h) {
    f32x4 acc1[2][2];  // [tt][mt]
#pragma unroll
    for (int tt = 0; tt < 2; ++tt)
#pragma unroll
      for (int mt = 0; mt < 2; ++mt) acc1[tt][mt] = (f32x4)0.f;

    // ---- GEMM1 quarter: no barriers; weights direct from L2, distance-2 prefetch ----
#pragma unroll
    for (int kk = 0; kk < 8; ++kk) {
      if (kk < 6) {
        wnxt0 = W1F(h, kk + 2, 0);
        wnxt1 = W1F(h, kk + 2, 1);
      } else {
        wnxt0 = W2F(h, kk - 6, 0);
        wnxt1 = W2F(h, kk - 6, 1);
      }
      bf16x8 xfr0, xfr1;
      {
        int byte0 = (l15 * 512 + kk * 64 + lg * 16) ^ ((l15 & 7) << 4);
        xfr0 = *(const bf16x8*)(Xb + byte0);
        int m = 16 + l15;
        int byte1 = (m * 512 + kk * 64 + lg * 16) ^ ((m & 7) << 4);
        xfr1 = *(const bf16x8*)(Xb + byte1);
      }
      __builtin_amdgcn_s_setprio(1);
      acc1[0][0] = __builtin_amdgcn_mfma_f32_16x16x32_bf16(wcur0, xfr0, acc1[0][0], 0, 0, 0);
      acc1[0][1] = __builtin_amdgcn_mfma_f32_16x16x32_bf16(wcur0, xfr1, acc1[0][1], 0, 0, 0);
      acc1[1][0] = __builtin_amdgcn_mfma_f32_16x16x32_bf16(wcur1, xfr0, acc1[1][0], 0, 0, 0);
      acc1[1][1] = __builtin_amdgcn_mfma_f32_16x16x32_bf16(wcur1, xfr1, acc1[1][1], 0, 0, 0);
      __builtin_amdgcn_s_setprio(0);
      wcur0 = wmid0; wcur1 = wmid1;
      wmid0 = wnxt0; wmid1 = wnxt1;
    }

    // ---- bias + relu + packed Hb store ----
#pragma unroll
    for (int tt = 0; tt < 2; ++tt) {
      f32x4 b1v = *(const f32x4*)&b1[h * 128 + w * 32 + tt * 16 + lg * 4];
#pragma unroll
      for (int mt = 0; mt < 2; ++mt) {
        f32x4 v = acc1[tt][mt] + b1v;
        v[0] = fmaxf(v[0], 0.f); v[1] = fmaxf(v[1], 0.f);
        v[2] = fmaxf(v[2], 0.f); v[3] = fmaxf(v[3], 0.f);
        int m = mt * 16 + l15;
        int n1l = w * 32 + tt * 16 + lg * 4;
        int byte = (m * 256 + n1l * 2) ^ ((m & 7) << 4);
        *(uint2*)(Hb + byte) = make_uint2(pk2(v[0], v[1]), pk2(v[2], v[3]));
      }
    }
    __syncthreads();  // Hb ready for all waves

    // ---- GEMM2 quarter: no barriers; weights direct from L2, distance-2 prefetch ----
#pragma unroll
    for (int q = 0; q < 8; ++q) {
      if (q < 6) {
        wnxt0 = W2F(h, q + 2, 0);
        wnxt1 = W2F(h, q + 2, 1);
      } else if (h < 3) {
        wnxt0 = W1F(h + 1, q - 6, 0);
        wnxt1 = W1F(h + 1, q - 6, 1);
      }
      int kk2 = q & 3, h2 = q >> 2;
      bf16x8 hfr0, hfr1;
      {
        int byte0 = (l15 * 256 + kk2 * 64 + lg * 16) ^ ((l15 & 7) << 4);
        hfr0 = *(const bf16x8*)(Hb + byte0);
        int m = 16 + l15;
        int byte1 = (m * 256 + kk2 * 64 + lg * 16) ^ ((m & 7) << 4);
        hfr1 = *(const bf16x8*)(Hb + byte1);
      }
      __builtin_amdgcn_s_setprio(1);
      acc2[0][h2 * 2 + 0] = __builtin_amdgcn_mfma_f32_16x16x32_bf16(hfr0, wcur0, acc2[0][h2 * 2 + 0], 0, 0, 0);
      acc2[0][h2 * 2 + 1] = __builtin_amdgcn_mfma_f32_16x16x32_bf16(hfr0, wcur1, acc2[0][h2 * 2 + 1], 0, 0, 0);
      acc2[1][h2 * 2 + 0] = __builtin_amdgcn_mfma_f32_16x16x32_bf16(hfr1, wcur0, acc2[1][h2 * 2 + 0], 0, 0, 0);
      acc2[1][h2 * 2 + 1] = __builtin_amdgcn_mfma_f32_16x16x32_bf16(hfr1, wcur1, acc2[1][h2 * 2 + 1], 0, 0, 0);
      __builtin_amdgcn_s_setprio(0);
      wcur0 = wmid0; wcur1 = wmid1;
      wmid0 = wnxt0; wmid1 = wnxt1;
    }
    __syncthreads();  // all waves done reading Hb before next h overwrites
  }
#undef W1F
#undef W2F

  // ---- row stats straight from acc2 registers ----
  {
#pragma unroll
    for (int mt = 0; mt < 2; ++mt)
#pragma unroll
      for (int jr = 0; jr < 4; ++jr) {
        float sv = 0.f, ssv = 0.f;
#pragma unroll
        for (int nfi = 0; nfi < 4; ++nfi) {
          int col = (nfi >> 1) * 128 + w * 32 + (nfi & 1) * 16 + l15;
          float v = acc2[mt][nfi][jr] + b2[col];
          sv += v;
          ssv += v * v;
        }
        sv += __shfl_xor(sv, 1); ssv += __shfl_xor(ssv, 1);
        sv += __shfl_xor(sv, 2); ssv += __shfl_xor(ssv, 2);
        sv += __shfl_xor(sv, 4); ssv += __shfl_xor(ssv, 4);
        sv += __shfl_xor(sv, 8); ssv += __shfl_xor(ssv, 8);
        if (l15 == 0) {
          int r = mt * 16 + lg * 4 + jr;
          psA[r * 4 + w] = sv;
          psB[r * 4 + w] = ssv;
        }
      }
  }
  __syncthreads();
  if (t < 32) {
    float sv = psA[t * 4] + psA[t * 4 + 1] + psA[t * 4 + 2] + psA[t * 4 + 3];
    float ssv = psB[t * 4] + psB[t * 4 + 1] + psB[t * 4 + 2] + psB[t * 4 + 3];
    float mean = sv * (1.f / 256.f);
    float var = ssv * (1.f / 256.f) - mean * mean;
    fstat[t * 2] = mean;
    fstat[t * 2 + 1] = rsqrtf(var + LNEPS);
  }
  __syncthreads();

  // ---- finalize straight from acc2: LN affine, graph_normal, residual, store (+pool) ----
  {
    int c0 = w * 32 + l15, c1 = c0 + 16, c2 = c0 + 128, c3 = c0 + 144;
    float b2v0 = b2[c0], b2v1 = b2[c1], b2v2 = b2[c2], b2v3 = b2[c3];
    float lgm0 = ln_g[c0], lgm1 = ln_g[c1], lgm2 = ln_g[c2], lgm3 = ln_g[c3];
    float lbm0 = ln_b[c0], lbm1 = ln_b[c1], lbm2 = ln_b[c2], lbm3 = ln_b[c3];
    float p0 = 0.f, p1 = 0.f, p2 = 0.f, p3 = 0.f;
    float crec = 0.f;
    int curg = -1;
#pragma unroll
    for (int mt = 0; mt < 2; ++mt) {
#pragma unroll
      for (int jr = 0; jr < 4; ++jr) {
        int r = mt * 16 + lg * 4 + jr;
        int gr = row0 + r;
        if (gr < M) {
          float mean = fstat[r * 2], rstd = fstat[r * 2 + 1];
          float gf = gfs[r];
          if (POOL) {
            int g = gid_s[r];
            if (g != curg) {
              if (curg >= 0) {
                atomicAdd(&pool_out[(size_t)curg * HDIM + c0], p0 * crec);
                atomicAdd(&pool_out[(size_t)curg * HDIM + c1], p1 * crec);
                atomicAdd(&pool_out[(size_t)curg * HDIM + c2], p2 * crec);
                atomicAdd(&pool_out[(size_t)curg * HDIM + c3], p3 * crec);
              }
              curg = g; crec = grs[r];
              p0 = 0.f; p1 = 0.f; p2 = 0.f; p3 = 0.f;
            }
          }
          const float* resp = residual + (size_t)gr * HDIM;
          float* outp = out_rows + (size_t)gr * HDIM;
          float v0 = ((acc2[mt][0][jr] + b2v0 - mean) * rstd * lgm0 + lbm0) * gf + resp[c0];
          float v1 = ((acc2[mt][1][jr] + b2v1 - mean) * rstd * lgm1 + lbm1) * gf + resp[c1];
          float v2 = ((acc2[mt][2][jr] + b2v2 - mean) * rstd * lgm2 + lbm2) * gf + resp[c2];
          float v3 = ((acc2[mt][3][jr] + b2v3 - mean) * rstd * lgm3 + lbm3) * gf + resp[c3];
          outp[c0] = v0; outp[c1] = v1; outp[c2] = v2; outp[c3] = v3;
          if (POOL) { p0 += v0; p1 += v1; p2 += v2; p3 += v3; }
        }
      }
    }
    if (POOL && curg >= 0) {
      atomicAdd(&pool_out[(size_t)curg * HDIM + c0], p0 * crec);
      atomicAdd(&pool_out[(size_t)curg * HDIM + c1], p1 * crec);
      atomicAdd(&pool_out[(size_t)curg * HDIM + c2], p2 * crec);
      atomicAdd(&pool_out[(size_t)curg * HDIM + c3], p3 * crec);
    }
  }
}

extern "C" void kernel_launch(void* const* d_in, const int* in_sizes, int n_in,
                              void* d_out, int out_size, void* d_ws, size_t ws_size,
                              hipStream_t stream) {
  const float* node_hidden = (const float*)d_in[0];
  const float* edge_hidden = (const float*)d_in[1];
  const float* bond_angle = (const float*)d_in[2];
  const int* ab_src = (const int*)d_in[3];
  const int* ab_dst = (const int*)d_in[4];
  const int* ba_src = (const int*)d_in[5];
  const int* ba_dst = (const int*)d_in[6];
  const int* node_gid = (const int*)d_in[7];
  const int* bond_gid = (const int*)d_in[8];
  const float* rbf_w = (const float*)d_in[10];
  const float* rbf_b = (const float*)d_in[11];
  const float* ba_w1 = (const float*)d_in[12];
  const float* ba_b1 = (const float*)d_in[13];
  const float* ba_w2 = (const float*)d_in[14];
  const float* ba_b2 = (const float*)d_in[15];
  const float* ba_ln_g = (const float*)d_in[16];
  const float* ba_ln_b = (const float*)d_in[17];
  const float* ab_w1 = (const float*)d_in[18];
  const float* ab_b1 = (const float*)d_in[19];
  const float* ab_w2 = (const float*)d_in[20];
  const float* ab_b2 = (const float*)d_in[21];
  const float* ab_ln_g = (const float*)d_in[22];
  const float* ab_ln_b = (const float*)d_in[23];

  int N = in_sizes[0] / HDIM;
  int E = in_sizes[1] / HDIM;
  int A = in_sizes[2];
  int G = out_size / HDIM - N - E;

  float* out_node = (float*)d_out;
  float* out_edge = out_node + (size_t)N * HDIM;
  float* out_graph = out_edge + (size_t)E * HDIM;

  // ---- workspace layout ----
  char* ws = (char*)d_ws;
  int* cnt_node = (int*)ws;                    // G   (zeroed)
  int* cnt_bond = cnt_node + G;                // G   (zeroed)
  int* deg_e = cnt_bond + G;                   // E   (zeroed)
  int* cur_e = deg_e + E;                      // E   (zeroed)
  int* deg_n = cur_e + E;                      // N   (zeroed)
  int* cur_n = deg_n + N;                      // N   (zeroed)
  size_t zero_bytes = (size_t)(2 * G + 2 * E + 2 * N) * 4;
  float* fac_node = (float*)(cur_n + N);       // G
  float* fac_bond = fac_node + G;              // G
  float* recip_node = fac_bond + G;            // G
  int* off_e = (int*)(recip_node + G);         // E
  int* csr_e = off_e + E;                      // A
  int* off_n = csr_e + A;                      // N
  int* csr_n = off_n + N;                      // E
  int* bsum = csr_n + E;                       // 1024 (E-part [0,512), N-part [512,768))
  size_t off = ((size_t)((char*)(bsum + 1024) - ws) + 255) & ~(size_t)255;
  unsigned short* w1p_ba = (unsigned short*)(ws + off); off += (size_t)512 * 256 * 2;
  unsigned short* w2p_ba = (unsigned short*)(ws + off); off += (size_t)256 * 512 * 2;
  unsigned short* w1p_ab = (unsigned short*)(ws + off); off += (size_t)512 * 256 * 2;
  unsigned short* w2p_ab = (unsigned short*)(ws + off); off += (size_t)256 * 512 * 2;

  hipMemsetAsync(d_ws, 0, zero_bytes, stream);
  hipMemsetAsync(out_graph, 0, (size_t)G * HDIM * 4, stream);

  pack_all_kernel<<<2048, 256, 0, stream>>>(ba_w1, ba_w2, ab_w1, ab_w2,
                                            w1p_ba, w2p_ba, w1p_ab, w2p_ab);

  prep_kernel<<<(A + 255) / 256, 256, 0, stream>>>(node_gid, bond_gid, ab_dst, ba_dst,
                                                   cnt_node, cnt_bond, deg_n, deg_e, N, E, A);

  int nbE = (E + 255) / 256;
  int nbN = (N + 255) / 256;
  int nbA = (A + 255) / 256;
  int nbG = (G + 255) / 256;
  scan1_both_kernel<<<nbE + nbN, 256, 0, stream>>>(deg_e, deg_n, off_e, off_n, bsum, E, N, nbE);
  scan2_both_kernel<<<2, 1024, 0, stream>>>(bsum, nbE, nbN);
  scan3f_kernel<<<nbE + nbN + nbG, 256, 0, stream>>>(off_e, off_n, bsum, cnt_node, cnt_bond,
                                                     fac_node, fac_bond, recip_node,
                                                     E, N, G, nbE, nbN);
  fill_both_kernel<<<nbA + nbE, 256, 0, stream>>>(ba_dst, ab_dst, off_e, off_n,
                                                  cur_e, cur_n, csr_e, csr_n, A, E, nbA);

  angle_gather_kernel<<<(E + 15) / 16, 256, 0, stream>>>(bond_angle, ba_src, edge_hidden,
                                                         off_e, deg_e, csr_e, rbf_w, rbf_b,
                                                         out_edge, E);
  mlp_kernel<0><<<(E + 31) / 32, 256, 0, stream>>>(out_edge, out_edge, edge_hidden, bond_gid,
                                                   fac_bond, nullptr, w1p_ba, ba_b1, w2p_ba,
                                                   ba_b2, ba_ln_g, ba_ln_b, nullptr, E);

  node_gather_kernel<<<(N + 3) / 4, 256, 0, stream>>>(node_hidden, out_edge, ab_src,
                                                      off_n, deg_n, csr_n, out_node, N);
  mlp_kernel<1><<<(N + 31) / 32, 256, 0, stream>>>(out_node, out_node, node_hidden, node_gid,
                                                   fac_node, recip_node, w1p_ab, ab_b1, w2p_ab,
                                                   ab_b2, ab_ln_g, ab_ln_b, out_graph, N);
}